// Round 1
// baseline (840.365 us; speedup 1.0000x reference)
//
#include <hip/hip_runtime.h>
#include <math.h>

#define BN 4
#define CN 64
#define HN 64
#define WN 256
#define ON 64
#define NOC 18
#define PN 9
#define HO 31
#define WO 127

__device__ __forceinline__ float trianglewave(float x) {
    const float PI_F = 3.14159274101257324f;   // float(np.pi)
    float n = floorf(x / PI_F + 0.5f);
    float m = fmodf(n, 2.0f);
    if (m < 0.0f) m += 2.0f;
    float sgn = 1.0f - 2.0f * m;
    return (x - PI_F * n) * sgn;
}

__device__ __forceinline__ float prak_f(float x) {
    const float PI_HALF = 1.57079637050628662f; // float(np.pi/2)
    return trianglewave(x) + trianglewave(x + PI_HALF);
}

// Transpose weights:
//  wA[c][k][oc]  (c*9+k)*18+oc   <- offset_w[((oc*64+c)*9+k)]
//  wB[p][c][o]   (p*64+c)*64+o   <- weight[(o*64+c)*9+p]
__global__ void prep_kernel(const float* __restrict__ offw,
                            const float* __restrict__ wgt,
                            float* __restrict__ wA,
                            float* __restrict__ wB) {
    int t = blockIdx.x * blockDim.x + threadIdx.x;
    if (t < CN * 9 * NOC) {
        int oc = t % NOC;
        int k  = (t / NOC) % 9;
        int c  = t / (NOC * 9);
        wA[t] = offw[(oc * CN + c) * 9 + k];
    }
    if (t < PN * CN * ON) {
        int o = t % ON;
        int c = (t / ON) % CN;
        int p = t / (ON * CN);
        wB[t] = wgt[(o * CN + c) * 9 + p];
    }
}

// offsets[b][oc][h][w] = bias[oc] + sum_{c,ky,kx} xpad[b,c,h+ky,w+kx] * offset_w[oc,c,ky,kx]
__global__ __launch_bounds__(256) void offsets_kernel(const float* __restrict__ x,
                                                      const float* __restrict__ wA,
                                                      const float* __restrict__ offb,
                                                      float* __restrict__ offs) {
    int t = blockIdx.x * 256 + threadIdx.x;
    int w = t % WN;
    int h = (t / WN) % HN;
    int b = t / (WN * HN);

    float acc[NOC];
#pragma unroll
    for (int i = 0; i < NOC; i++) acc[i] = 0.0f;

    const float* xb = x + (size_t)b * CN * HN * WN;
    for (int c = 0; c < CN; c++) {
        const float* xc = xb + c * HN * WN;
#pragma unroll
        for (int k = 0; k < 9; k++) {
            int ky = k / 3, kx = k % 3;
            int iy = h + ky - 1;
            int ix = w + kx - 1;
            float xv = 0.0f;
            if (iy >= 0 && iy < HN && ix >= 0 && ix < WN) xv = xc[iy * WN + ix];
            const float* wa = wA + (c * 9 + k) * NOC;
#pragma unroll
            for (int oc = 0; oc < NOC; oc++) acc[oc] += xv * wa[oc];
        }
    }
#pragma unroll
    for (int oc = 0; oc < NOC; oc++)
        offs[((b * NOC + oc) * HN + h) * WN + w] = acc[oc] + offb[oc];
}

// Deformable conv + fused partial stats.
// block: (64 w-lanes, 2 o-halves); grid: (W/64, H, B)
__global__ __launch_bounds__(128) void deform_kernel(const float* __restrict__ x,
                                                     const float* __restrict__ offs,
                                                     const float* __restrict__ mask,
                                                     const float* __restrict__ wB,
                                                     float* __restrict__ y,
                                                     float2* __restrict__ partials) {
    int wlane = threadIdx.x;           // 0..63
    int ohalf = threadIdx.y;           // 0..1
    int w = blockIdx.x * 64 + wlane;
    int h = blockIdx.y;
    int b = blockIdx.z;
    int obase = ohalf * 32;

    float acc[32];
#pragma unroll
    for (int i = 0; i < 32; i++) acc[i] = 0.0f;

    const float* xb = x + (size_t)b * CN * HN * WN;

    for (int p = 0; p < PN; p++) {
        float offy = offs[((b * NOC + 2 * p) * HN + h) * WN + w];
        float offx = offs[((b * NOC + 2 * p + 1) * HN + h) * WN + w];
        float mk   = mask[((b * PN + p) * HN + h) * WN + w];

        float py = (float)(h + p / 3) + offy;   // padded space
        float px = (float)(w + p % 3) + offx;
        float fy0 = floorf(py);
        float fx0 = floorf(px);
        float wy1 = py - fy0, wx1 = px - fx0;
        float wy0 = 1.0f - wy1, wx0 = 1.0f - wx1;

        int iy0 = (int)fy0 - 1;   // x-space top-left corner
        int ix0 = (int)fx0 - 1;
        int iy1 = iy0 + 1, ix1 = ix0 + 1;
        bool vy0 = (iy0 >= 0) && (iy0 < HN);
        bool vy1 = (iy1 >= 0) && (iy1 < HN);
        bool vx0 = (ix0 >= 0) && (ix0 < WN);
        bool vx1 = (ix1 >= 0) && (ix1 < WN);

        float w00 = (vy0 && vx0) ? wy0 * wx0 * mk : 0.0f;
        float w01 = (vy0 && vx1) ? wy0 * wx1 * mk : 0.0f;
        float w10 = (vy1 && vx0) ? wy1 * wx0 * mk : 0.0f;
        float w11 = (vy1 && vx1) ? wy1 * wx1 * mk : 0.0f;

        int cy0 = min(max(iy0, 0), HN - 1), cy1 = min(max(iy1, 0), HN - 1);
        int cx0 = min(max(ix0, 0), WN - 1), cx1 = min(max(ix1, 0), WN - 1);
        int a00 = cy0 * WN + cx0, a01 = cy0 * WN + cx1;
        int a10 = cy1 * WN + cx0, a11 = cy1 * WN + cx1;

        const float* wp = wB + (p * CN) * ON + obase;
        const float* xc = xb;
        for (int c = 0; c < CN; c++, xc += HN * WN) {
            float v = w00 * xc[a00] + w01 * xc[a01] + w10 * xc[a10] + w11 * xc[a11];
            const float* wc = wp + c * ON;
#pragma unroll
            for (int o = 0; o < 32; o++) acc[o] += wc[o] * v;
        }
    }

    float s1 = 0.0f, s2 = 0.0f;
#pragma unroll
    for (int o = 0; o < 32; o++) {
        y[((b * ON + obase + o) * HN + h) * WN + w] = acc[o];
        s1 += acc[o];
        s2 += acc[o] * acc[o];
    }

    __shared__ float red1[128], red2[128];
    int tid = threadIdx.y * 64 + threadIdx.x;
    red1[tid] = s1;
    red2[tid] = s2;
    __syncthreads();
    for (int s = 64; s > 0; s >>= 1) {
        if (tid < s) { red1[tid] += red1[tid + s]; red2[tid] += red2[tid + s]; }
        __syncthreads();
    }
    if (tid == 0) {
        int blin = (blockIdx.z * gridDim.y + blockIdx.y) * gridDim.x + blockIdx.x;
        partials[blin] = make_float2(red1[0], red2[0]);
    }
}

__global__ __launch_bounds__(256) void stats_kernel(const float2* __restrict__ partials,
                                                    int nblocks,
                                                    float* __restrict__ stats) {
    __shared__ double r1[256], r2[256];
    int tid = threadIdx.x;
    double s1 = 0.0, s2 = 0.0;
    for (int i = tid; i < nblocks; i += 256) {
        s1 += (double)partials[i].x;
        s2 += (double)partials[i].y;
    }
    r1[tid] = s1;
    r2[tid] = s2;
    __syncthreads();
    for (int s = 128; s > 0; s >>= 1) {
        if (tid < s) { r1[tid] += r1[tid + s]; r2[tid] += r2[tid + s]; }
        __syncthreads();
    }
    if (tid == 0) {
        double N = (double)BN * ON * HN * WN;
        double mu = r1[0] / N;
        double var = r2[0] / N - mu * mu;
        stats[0] = (float)mu;
        stats[1] = (float)(1.0 / sqrt(var + 1e-5));
    }
}

// normalize + prak + concat(x) + 3x3/2 maxpool
__global__ __launch_bounds__(256) void out_kernel(const float* __restrict__ yb,
                                                  const float* __restrict__ x,
                                                  const float* __restrict__ stats,
                                                  float* __restrict__ out) {
    int t = blockIdx.x * 256 + threadIdx.x;
    if (t >= BN * 128 * HO * WO) return;
    int ow = t % WO;
    int oh = (t / WO) % HO;
    int ch = (t / (WO * HO)) % 128;
    int b  = t / (WO * HO * 128);

    float mu = stats[0];
    float inv = stats[1];
    float m = -INFINITY;
    if (ch < 64) {
        const float* yc = yb + ((size_t)(b * ON + ch) * HN) * WN;
#pragma unroll
        for (int dy = 0; dy < 3; dy++) {
            const float* row = yc + (2 * oh + dy) * WN + 2 * ow;
#pragma unroll
            for (int dx = 0; dx < 3; dx++) {
                float v = prak_f((row[dx] - mu) * inv);
                m = fmaxf(m, v);
            }
        }
    } else {
        const float* xc = x + ((size_t)(b * CN + (ch - 64)) * HN) * WN;
#pragma unroll
        for (int dy = 0; dy < 3; dy++) {
            const float* row = xc + (2 * oh + dy) * WN + 2 * ow;
#pragma unroll
            for (int dx = 0; dx < 3; dx++) m = fmaxf(m, row[dx]);
        }
    }
    out[t] = m;
}

extern "C" void kernel_launch(void* const* d_in, const int* in_sizes, int n_in,
                              void* d_out, int out_size, void* d_ws, size_t ws_size,
                              hipStream_t stream) {
    const float* x    = (const float*)d_in[0];
    const float* offw = (const float*)d_in[1];
    const float* offb = (const float*)d_in[2];
    const float* wgt  = (const float*)d_in[3];
    const float* mask = (const float*)d_in[4];
    float* out = (float*)d_out;

    float* ws = (float*)d_ws;
    float* wA   = ws;                       // 10368
    float* wB   = wA + 10368;               // 36864
    float* offs = wB + 36864;               // 1179648
    float* y    = offs + 1179648;           // 4194304
    float2* partials = (float2*)(y + 4194304);  // 1024 float2
    float* stats = (float*)(partials + 1024);   // 2 floats

    prep_kernel<<<144, 256, 0, stream>>>(offw, wgt, wA, wB);
    offsets_kernel<<<256, 256, 0, stream>>>(x, wA, offb, offs);
    deform_kernel<<<dim3(4, 64, 4), dim3(64, 2), 0, stream>>>(x, offs, mask, wB, y, partials);
    stats_kernel<<<1, 256, 0, stream>>>(partials, 1024, stats);
    out_kernel<<<7874, 256, 0, stream>>>(y, x, stats, out);
}

// Round 2
// 612.388 us; speedup vs baseline: 1.3723x; 1.3723x over previous
//
#include <hip/hip_runtime.h>
#include <math.h>

#define BN 4
#define CN 64
#define HN 64
#define WN 256
#define ON 64
#define NOC 18
#define PN 9
#define HO 31
#define WO 127

__device__ __forceinline__ float trianglewave(float x) {
    const float PI_F = 3.14159274101257324f;   // float(np.pi)
    float n = floorf(x / PI_F + 0.5f);
    float m = fmodf(n, 2.0f);
    if (m < 0.0f) m += 2.0f;
    float sgn = 1.0f - 2.0f * m;
    return (x - PI_F * n) * sgn;
}

__device__ __forceinline__ float prak_f(float x) {
    const float PI_HALF = 1.57079637050628662f; // float(np.pi/2)
    return trianglewave(x) + trianglewave(x + PI_HALF);
}

// Transpose weights:
//  wA[c][k][oc]  (c*9+k)*18+oc   <- offset_w[((oc*64+c)*9+k)]
//  wB[p][c][o]   (p*64+c)*64+o   <- weight[(o*64+c)*9+p]
__global__ void prep_kernel(const float* __restrict__ offw,
                            const float* __restrict__ wgt,
                            float* __restrict__ wA,
                            float* __restrict__ wB) {
    int t = blockIdx.x * blockDim.x + threadIdx.x;
    if (t < CN * 9 * NOC) {
        int oc = t % NOC;
        int k  = (t / NOC) % 9;
        int c  = t / (NOC * 9);
        wA[t] = offw[(oc * CN + c) * 9 + k];
    }
    if (t < PN * CN * ON) {
        int o = t % ON;
        int c = (t / ON) % CN;
        int p = t / (ON * CN);
        wB[t] = wgt[(o * CN + c) * 9 + p];
    }
}

// block (64 w-lanes, 4 c-groups); grid 1024 with XCD-chunked swizzle
__global__ __launch_bounds__(256) void offsets_kernel(const float* __restrict__ x,
                                                      const float* __restrict__ wA,
                                                      const float* __restrict__ offb,
                                                      float* __restrict__ offs) {
    __shared__ float red[4][64][19];
    int bid = blockIdx.x;
    int logical = ((bid & 7) << 7) + (bid >> 3);  // contiguous 128-chunk per XCD
    int b = logical >> 8;
    int h = (logical >> 2) & 63;
    int wblk = logical & 3;
    int wlane = threadIdx.x;
    int cg = threadIdx.y;
    int w = (wblk << 6) + wlane;

    float acc[NOC];
#pragma unroll
    for (int i = 0; i < NOC; i++) acc[i] = 0.0f;

    const float* xc = x + ((size_t)b * CN + cg * 16) * HN * WN;
    for (int c = 0; c < 16; c++, xc += HN * WN) {
        const float* wa = wA + ((cg * 16 + c) * 9) * NOC;
#pragma unroll
        for (int k = 0; k < 9; k++) {
            int iy = h + k / 3 - 1;
            int ix = w + k % 3 - 1;
            float xv = (iy >= 0 && iy < HN && ix >= 0 && ix < WN) ? xc[iy * WN + ix] : 0.0f;
#pragma unroll
            for (int oc = 0; oc < NOC; oc++) acc[oc] += xv * wa[k * NOC + oc];
        }
    }
#pragma unroll
    for (int oc = 0; oc < NOC; oc++) red[cg][wlane][oc] = acc[oc];
    __syncthreads();
    if (cg == 0) {
#pragma unroll
        for (int oc = 0; oc < NOC; oc++) {
            float t = red[0][wlane][oc] + red[1][wlane][oc] +
                      red[2][wlane][oc] + red[3][wlane][oc] + offb[oc];
            offs[((b * NOC + oc) * HN + h) * WN + w] = t;
        }
    }
}

// Deformable conv + fused partial stats.
// block: (64 w, 2 o-halves, 2 c-halves); grid 1024 XCD-swizzled
__global__ __launch_bounds__(256) void deform_kernel(const float* __restrict__ x,
                                                     const float* __restrict__ offs,
                                                     const float* __restrict__ mask,
                                                     const float* __restrict__ wB,
                                                     float* __restrict__ y,
                                                     float2* __restrict__ partials) {
    __shared__ float red[64 * 65];      // cg=1 acc spill, padded stride 65
    __shared__ float red1[128], red2[128];

    int bid = blockIdx.x;
    int logical = ((bid & 7) << 7) + (bid >> 3);
    int b = logical >> 8;
    int h = (logical >> 2) & 63;
    int wblk = logical & 3;
    int wlane = threadIdx.x;            // 0..63
    int og = threadIdx.y;               // 0..1
    int cg = threadIdx.z;               // 0..1
    int w = (wblk << 6) + wlane;
    int obase = og << 5;
    int cbase = cg << 5;

    float acc[32];
#pragma unroll
    for (int i = 0; i < 32; i++) acc[i] = 0.0f;

    const float* xb = x + ((size_t)b * CN + cbase) * HN * WN;

    for (int p = 0; p < PN; p++) {
        float offy = offs[((b * NOC + 2 * p) * HN + h) * WN + w];
        float offx = offs[((b * NOC + 2 * p + 1) * HN + h) * WN + w];
        float mk   = mask[((b * PN + p) * HN + h) * WN + w];

        float py = (float)(h + p / 3) + offy;   // padded space
        float px = (float)(w + p % 3) + offx;
        float fy0 = floorf(py);
        float fx0 = floorf(px);
        float wy1 = py - fy0, wx1 = px - fx0;
        float wy0 = 1.0f - wy1, wx0 = 1.0f - wx1;

        int iy0 = (int)fy0 - 1;   // x-space top-left corner
        int ix0 = (int)fx0 - 1;
        int iy1 = iy0 + 1, ix1 = ix0 + 1;
        bool vy0 = (iy0 >= 0) && (iy0 < HN);
        bool vy1 = (iy1 >= 0) && (iy1 < HN);
        bool vx0 = (ix0 >= 0) && (ix0 < WN);
        bool vx1 = (ix1 >= 0) && (ix1 < WN);

        float w00 = (vy0 && vx0) ? wy0 * wx0 * mk : 0.0f;
        float w01 = (vy0 && vx1) ? wy0 * wx1 * mk : 0.0f;
        float w10 = (vy1 && vx0) ? wy1 * wx0 * mk : 0.0f;
        float w11 = (vy1 && vx1) ? wy1 * wx1 * mk : 0.0f;

        int cy0 = min(max(iy0, 0), HN - 1), cy1 = min(max(iy1, 0), HN - 1);
        int cx0 = min(max(ix0, 0), WN - 1), cx1 = min(max(ix1, 0), WN - 1);
        int a00 = cy0 * WN + cx0, a01 = cy0 * WN + cx1;
        int a10 = cy1 * WN + cx0, a11 = cy1 * WN + cx1;

        const float* wp = wB + (p * CN + cbase) * ON + obase;
        const float* xc = xb;
#pragma unroll 4
        for (int c = 0; c < 32; c++, xc += HN * WN) {
            float v = w00 * xc[a00] + w01 * xc[a01] + w10 * xc[a10] + w11 * xc[a11];
            const float* wc = wp + c * ON;
#pragma unroll
            for (int o = 0; o < 32; o++) acc[o] += wc[o] * v;
        }
    }

    // reduce the two c-halves
    if (cg == 1) {
        float* dst = red + wlane * 65 + obase;
#pragma unroll
        for (int o = 0; o < 32; o++) dst[o] = acc[o];
    }
    __syncthreads();

    float s1 = 0.0f, s2 = 0.0f;
    if (cg == 0) {
        const float* src = red + wlane * 65 + obase;
#pragma unroll
        for (int o = 0; o < 32; o++) {
            float t = acc[o] + src[o];
            y[((b * ON + obase + o) * HN + h) * WN + w] = t;
            s1 += t;
            s2 += t * t;
        }
        int tid128 = og * 64 + wlane;
        red1[tid128] = s1;
        red2[tid128] = s2;
    }
    __syncthreads();
    int tid128 = og * 64 + wlane;
    for (int s = 64; s > 0; s >>= 1) {
        if (cg == 0 && tid128 < s) {
            red1[tid128] += red1[tid128 + s];
            red2[tid128] += red2[tid128 + s];
        }
        __syncthreads();
    }
    if (cg == 0 && tid128 == 0)
        partials[blockIdx.x] = make_float2(red1[0], red2[0]);
}

__global__ __launch_bounds__(256) void stats_kernel(const float2* __restrict__ partials,
                                                    int nblocks,
                                                    float* __restrict__ stats) {
    __shared__ double r1[256], r2[256];
    int tid = threadIdx.x;
    double s1 = 0.0, s2 = 0.0;
    for (int i = tid; i < nblocks; i += 256) {
        s1 += (double)partials[i].x;
        s2 += (double)partials[i].y;
    }
    r1[tid] = s1;
    r2[tid] = s2;
    __syncthreads();
    for (int s = 128; s > 0; s >>= 1) {
        if (tid < s) { r1[tid] += r1[tid + s]; r2[tid] += r2[tid + s]; }
        __syncthreads();
    }
    if (tid == 0) {
        double N = (double)BN * ON * HN * WN;
        double mu = r1[0] / N;
        double var = r2[0] / N - mu * mu;
        stats[0] = (float)mu;
        stats[1] = (float)(1.0 / sqrt(var + 1e-5));
    }
}

// normalize + prak + concat(x) + 3x3/2 maxpool
__global__ __launch_bounds__(256) void out_kernel(const float* __restrict__ yb,
                                                  const float* __restrict__ x,
                                                  const float* __restrict__ stats,
                                                  float* __restrict__ out) {
    int t = blockIdx.x * 256 + threadIdx.x;
    if (t >= BN * 128 * HO * WO) return;
    int ow = t % WO;
    int oh = (t / WO) % HO;
    int ch = (t / (WO * HO)) % 128;
    int b  = t / (WO * HO * 128);

    float mu = stats[0];
    float inv = stats[1];
    float m = -INFINITY;
    if (ch < 64) {
        const float* yc = yb + ((size_t)(b * ON + ch) * HN) * WN;
#pragma unroll
        for (int dy = 0; dy < 3; dy++) {
            const float* row = yc + (2 * oh + dy) * WN + 2 * ow;
#pragma unroll
            for (int dx = 0; dx < 3; dx++) {
                float v = prak_f((row[dx] - mu) * inv);
                m = fmaxf(m, v);
            }
        }
    } else {
        const float* xc = x + ((size_t)(b * CN + (ch - 64)) * HN) * WN;
#pragma unroll
        for (int dy = 0; dy < 3; dy++) {
            const float* row = xc + (2 * oh + dy) * WN + 2 * ow;
#pragma unroll
            for (int dx = 0; dx < 3; dx++) m = fmaxf(m, row[dx]);
        }
    }
    out[t] = m;
}

extern "C" void kernel_launch(void* const* d_in, const int* in_sizes, int n_in,
                              void* d_out, int out_size, void* d_ws, size_t ws_size,
                              hipStream_t stream) {
    const float* x    = (const float*)d_in[0];
    const float* offw = (const float*)d_in[1];
    const float* offb = (const float*)d_in[2];
    const float* wgt  = (const float*)d_in[3];
    const float* mask = (const float*)d_in[4];
    float* out = (float*)d_out;

    float* ws = (float*)d_ws;
    float* wA   = ws;                       // 10368
    float* wB   = wA + 10368;               // 36864
    float* offs = wB + 36864;               // 1179648
    float* y    = offs + 1179648;           // 4194304
    float2* partials = (float2*)(y + 4194304);  // 1024 float2
    float* stats = (float*)(partials + 1024);   // 2 floats

    prep_kernel<<<144, 256, 0, stream>>>(offw, wgt, wA, wB);
    offsets_kernel<<<1024, dim3(64, 4), 0, stream>>>(x, wA, offb, offs);
    deform_kernel<<<1024, dim3(64, 2, 2), 0, stream>>>(x, offs, mask, wB, y, partials);
    stats_kernel<<<1, 256, 0, stream>>>(partials, 1024, stats);
    out_kernel<<<7874, 256, 0, stream>>>(y, x, stats, out);
}